// Round 15
// baseline (117.697 us; speedup 1.0000x reference)
//
#include <hip/hip_runtime.h>
#include <hip/hip_bf16.h>

#define B    64
#define T    4096
#define V    64
#define NQ   64      // NGRAN * NGLIMPSE
#define NHID 2048
#define KDIM 4096    // V * NQ
#define FAN  4097    // KDIM + 1 (l_t column)

#define NT     32    // h rows per gemm block (2 MFMA n-tiles)
#define SPLITS 16    // K-split across gemm blocks
#define KC     (KDIM / SPLITS)   // 256 k per block
#define LDA    (KC + 8)          // LDS row stride (bf16): 528B -> ~2-way banks

typedef __attribute__((ext_vector_type(8))) short bf16x8;
typedef __attribute__((ext_vector_type(4))) float f32x4;

static __device__ __forceinline__ short f2bf(float x) {
    union { float f; unsigned u; } c; c.f = x;
    unsigned r = c.u + 0x7fff + ((c.u >> 16) & 1);   // RNE
    return (short)(r >> 16);
}

// ---------------------------------------------------------------------------
// Kernel 1: glimpse interpolation (~5-6 us measured). grid = (B, NQ),
// block = 64 (lane = v). Writes g_bf16[b][k] (k=v*NQ+q), out2, and zeroes
// out[] slice for the gemm's atomicAdd (stream-ordered before gemm).
// ---------------------------------------------------------------------------
__global__ __launch_bounds__(64) void glimpse_kernel(
    const float* __restrict__ vals, const float* __restrict__ time_,
    const int* __restrict__ masks, const float* __restrict__ l_t,
    unsigned short* __restrict__ g_bf, float* __restrict__ out2,
    float* __restrict__ out)
{
    const int b = blockIdx.x;
    const int q = blockIdx.y;
    const int v = threadIdx.x;

    if (v < 32) out[(size_t)b * NHID + q * 32 + v] = 0.0f;

    const float* t = time_ + (size_t)b * T;
    const float tmax = t[T - 1];          // times sorted ascending

    const int   j = q & 31;
    const float s = (q < 32) ? 1.0f : 5.0f;
    const float a = 0.5f * 0.1f * s;      // gwidth*s/2
    const float step = (2.0f * a) / 31.0f;
    float lin = (j == 31) ? a : (-a + step * (float)j);
    const float r = (lin + l_t[b]) * tmax;

    // binary search: p = first index with t[p] > r  (wave-uniform)
    int lo = 0, hi = T;
    while (lo < hi) {
        int mid = (lo + hi) >> 1;
        if (t[mid] > r) hi = mid; else lo = mid + 1;
    }
    const int p = lo;

    const int*   m  = masks + (size_t)b * T * V + v;
    const float* vv = vals  + (size_t)b * T * V + v;

    int i0 = -1;
    for (int i = p - 1; i >= 0; --i) {
        if (m[(size_t)i * V] != 0) { i0 = i; break; }
    }
    int i1 = -1;
    for (int i = p; i < T; ++i) {
        if (m[(size_t)i * V] != 0) { i1 = i; break; }
    }

    float y;
    if (i0 < 0 && i1 < 0) {
        y = 0.0f;
    } else if (i0 < 0) {
        y = vv[(size_t)i1 * V];
    } else if (i1 < 0) {
        y = vv[(size_t)i0 * V];
    } else {
        float t0 = t[i0], t1 = t[i1];
        float v0 = vv[(size_t)i0 * V], v1 = vv[(size_t)i1 * V];
        float den = (t1 > t0) ? (t1 - t0) : 1.0f;
        float w = (r - t0) / den;
        w = fminf(fmaxf(w, 0.0f), 1.0f);
        y = v0 + w * (v1 - v0);
    }

    const int k = v * NQ + q;
    g_bf[(size_t)b * KDIM + k] = (unsigned short)f2bf(y);
    if (k == KDIM / 2) out2[b] = y;             // g[:, 2048], fp32
}

// ---------------------------------------------------------------------------
// Kernel 2: MFMA GEMM (R14 structure) — DIAGNOSTIC mrep wraps the ENTIRE
// {stage A, stage W, barrier, MFMA} phase so the kernel's dur exceeds the
// ~39us harness-fill cutoff and its PMC row finally surfaces. Reps 2..32
// re-stage from warm L2 (marginal ~1.3us). acc accumulates mrep x, exact
// 1/32 rescale. grid = (NHID/NT, SPLITS) = (64,16) x 256 thr (4 waves).
// ---------------------------------------------------------------------------
__global__ __launch_bounds__(256) void gemm_mfma(
    const unsigned short* __restrict__ g_bf, const float* __restrict__ l_t,
    const float* __restrict__ W, const float* __restrict__ bias,
    float* __restrict__ out, int mrep, float scale)
{
    __shared__ unsigned short alds[B][LDA];     // 33.0 KB
    __shared__ unsigned short wlds[NT][LDA];    // 16.5 KB
    const int tid  = threadIdx.x;
    const int lane = tid & 63;
    const int wave = tid >> 6;
    const int l15  = lane & 15;
    const int lk   = lane >> 4;                 // k-group 0..3
    const int hbase = blockIdx.x * NT;
    const int s     = blockIdx.y;
    const int kbase = s * KC;

    f32x4 acc[2];
    acc[0] = (f32x4){0.f, 0.f, 0.f, 0.f};
    acc[1] = (f32x4){0.f, 0.f, 0.f, 0.f};

    for (int rep = 0; rep < mrep; ++rep) {
        // ---- stage A: 64 rows x 256 cols bf16, 16B chunks, coalesced ----
        #pragma unroll
        for (int i = 0; i < (B * KC) / (256 * 8); ++i) {   // 8 iters
            const int c   = tid + i * 256;
            const int row = c >> 5;                 // 32 chunks per row
            const int c8  = (c & 31) << 3;
            *(bf16x8*)&alds[row][c8] =
                *(const bf16x8*)(g_bf + (size_t)row * KDIM + kbase + c8);
        }
        // ---- stage W: 32 rows x 256 cols fp32 -> bf16, scalar coalesced ----
        #pragma unroll
        for (int i = 0; i < (NT * KC) / 256; ++i) {        // 32 iters
            const int c   = tid + i * 256;
            const int row = c >> 8;                 // 256 floats per row
            const int col = c & (KC - 1);
            wlds[row][col] =
                (unsigned short)f2bf(W[(size_t)(hbase + row) * FAN + kbase + col]);
        }
        __syncthreads();

        #pragma unroll
        for (int ks = 0; ks < KC; ks += 32) {
            const int kl = ks + lk * 8;
            const bf16x8 afrag = *(const bf16x8*)&alds[wave * 16 + l15][kl];
            #pragma unroll
            for (int nt = 0; nt < 2; ++nt) {
                const bf16x8 bfrag = *(const bf16x8*)&wlds[nt * 16 + l15][kl];
                acc[nt] = __builtin_amdgcn_mfma_f32_16x16x32_bf16(afrag, bfrag, acc[nt], 0, 0, 0);
            }
        }
        __syncthreads();
        asm volatile("" ::: "memory");   // force genuine re-staging next rep
    }

    acc[0] = acc[0] * scale;
    acc[1] = acc[1] * scale;

    // C/D layout: col = lane&15 (h offset), row = (lane>>4)*4 + reg (b offset)
    #pragma unroll
    for (int nt = 0; nt < 2; ++nt) {
        const int h = hbase + nt * 16 + l15;
        #pragma unroll
        for (int r = 0; r < 4; ++r) {
            const int b = wave * 16 + lk * 4 + r;
            float v = acc[nt][r];
            if (s == 0)
                v += bias[h] + l_t[b] * W[(size_t)h * FAN + KDIM];
            atomicAdd(&out[(size_t)b * NHID + h], v);
        }
    }
}

extern "C" void kernel_launch(void* const* d_in, const int* in_sizes, int n_in,
                              void* d_out, int out_size, void* d_ws, size_t ws_size,
                              hipStream_t stream) {
    const float* vals  = (const float*)d_in[0];
    const float* time_ = (const float*)d_in[1];
    const int*   masks = (const int*)d_in[2];
    // d_in[3] = lengths (all == T, unused)
    const float* l_t   = (const float*)d_in[4];
    const float* W     = (const float*)d_in[5];
    const float* bias  = (const float*)d_in[6];

    float* out  = (float*)d_out;                 // grep [B, NHID]
    float* out2 = out + (size_t)B * NHID;        // g[:, 2048]  [B]
    unsigned short* g_bf = (unsigned short*)d_ws; // bf16 [B][KDIM] = 512 KB

    dim3 g1(B, NQ);
    glimpse_kernel<<<g1, 64, 0, stream>>>(vals, time_, masks, l_t, g_bf, out2, out);

    dim3 g2(NHID / NT, SPLITS);
    gemm_mfma<<<g2, 256, 0, stream>>>(g_bf, l_t, W, bias, out, 32, 1.0f / 32.0f);
}

// Round 16
// 30.045 us; speedup vs baseline: 3.9174x; 3.9174x over previous
//
#include <hip/hip_runtime.h>
#include <hip/hip_bf16.h>

#define B    64
#define T    4096
#define V    64
#define NQ   64      // NGRAN * NGLIMPSE
#define NHID 2048
#define KDIM 4096    // V * NQ
#define FAN  4097    // KDIM + 1 (l_t column)

#define NT     16    // h rows per gemm block
#define SPLITS 16    // K-split across gemm blocks
#define KC     256   // k per block (KDIM/SPLITS)

typedef __attribute__((ext_vector_type(8))) short bf16x8;
typedef __attribute__((ext_vector_type(4))) float f32x4;

static __device__ __forceinline__ short f2bf(float x) {
    union { float f; unsigned u; } c; c.f = x;
    unsigned r = c.u + 0x7fff + ((c.u >> 16) & 1);   // RNE
    return (short)(r >> 16);
}

static __device__ __forceinline__ void load_lds16(const void* g, void* l) {
    __builtin_amdgcn_global_load_lds(
        (const __attribute__((address_space(1))) void*)g,
        (__attribute__((address_space(3))) void*)l, 16, 0, 0);
}

static __device__ __forceinline__ unsigned cvt_pk(float lo, float hi) {
    unsigned r;
    asm volatile("v_cvt_pk_bf16_f32 %0, %1, %2" : "=v"(r) : "v"(lo), "v"(hi));
    return r;
}

// ---------------------------------------------------------------------------
// Kernel 1: glimpse interpolation (~5-6 us measured). grid = (B, NQ),
// block = 64 (lane = v). Writes g_bf16[b][k] (k=v*NQ+q), out2, and zeroes
// out[] slice for the gemm's atomicAdd (stream-ordered before gemm).
// ---------------------------------------------------------------------------
__global__ __launch_bounds__(64) void glimpse_kernel(
    const float* __restrict__ vals, const float* __restrict__ time_,
    const int* __restrict__ masks, const float* __restrict__ l_t,
    unsigned short* __restrict__ g_bf, float* __restrict__ out2,
    float* __restrict__ out)
{
    const int b = blockIdx.x;
    const int q = blockIdx.y;
    const int v = threadIdx.x;

    if (v < 32) out[(size_t)b * NHID + q * 32 + v] = 0.0f;

    const float* t = time_ + (size_t)b * T;
    const float tmax = t[T - 1];          // times sorted ascending

    const int   j = q & 31;
    const float s = (q < 32) ? 1.0f : 5.0f;
    const float a = 0.5f * 0.1f * s;      // gwidth*s/2
    const float step = (2.0f * a) / 31.0f;
    float lin = (j == 31) ? a : (-a + step * (float)j);
    const float r = (lin + l_t[b]) * tmax;

    // binary search: p = first index with t[p] > r  (wave-uniform)
    int lo = 0, hi = T;
    while (lo < hi) {
        int mid = (lo + hi) >> 1;
        if (t[mid] > r) hi = mid; else lo = mid + 1;
    }
    const int p = lo;

    const int*   m  = masks + (size_t)b * T * V + v;
    const float* vv = vals  + (size_t)b * T * V + v;

    int i0 = -1;
    for (int i = p - 1; i >= 0; --i) {
        if (m[(size_t)i * V] != 0) { i0 = i; break; }
    }
    int i1 = -1;
    for (int i = p; i < T; ++i) {
        if (m[(size_t)i * V] != 0) { i1 = i; break; }
    }

    float y;
    if (i0 < 0 && i1 < 0) {
        y = 0.0f;
    } else if (i0 < 0) {
        y = vv[(size_t)i1 * V];
    } else if (i1 < 0) {
        y = vv[(size_t)i0 * V];
    } else {
        float t0 = t[i0], t1 = t[i1];
        float v0 = vv[(size_t)i0 * V], v1 = vv[(size_t)i1 * V];
        float den = (t1 > t0) ? (t1 - t0) : 1.0f;
        float w = (r - t0) / den;
        w = fminf(fmaxf(w, 0.0f), 1.0f);
        y = v0 + w * (v1 - v0);
    }

    const int k = v * NQ + q;
    g_bf[(size_t)b * KDIM + k] = (unsigned short)f2bf(y);
    if (k == KDIM / 2) out2[b] = y;             // g[:, 2048], fp32
}

// ---------------------------------------------------------------------------
// Kernel 2: MFMA GEMM with global_load_lds staging (full MLP on cold fetch:
// no VGPR round-trip, no waitcnt batching) + both-sides XOR swizzle (rule
// #21: inverse-swizzled global SOURCE per lane, swizzled LDS READ) to kill
// the 12.6M 16-way bank conflicts R15 exposed.
// grid = (NHID/NT, SPLITS) = (128,16) = 2048 blocks x 256 thr (4 waves).
// A: g_bf[64][kbase..+256] bf16 -> alds (32KB, 16B chunks, chunk c of row r
//    stored at position c^(r&7) within the row). W: fp32 [16][256] -> wlds
//    (16KB, same swizzle, 4-float chunks); B-frags cvt_pk'd at read time.
// Wave w: m-rows [16w,16w+16) x 16 h x 256 k = 8 MFMAs. atomicAdd tail
// (out pre-zeroed by glimpse).
// ---------------------------------------------------------------------------
__global__ __launch_bounds__(256) void gemm_mfma(
    const unsigned short* __restrict__ g_bf, const float* __restrict__ l_t,
    const float* __restrict__ W, const float* __restrict__ bias,
    float* __restrict__ out)
{
    __shared__ unsigned short alds[B * KC];     // 32 KB
    __shared__ float wlds[NT * KC];             // 16 KB
    const int tid  = threadIdx.x;
    const int l    = tid & 63;
    const int w    = tid >> 6;
    const int l15  = l & 15;
    const int lk   = l >> 4;                    // k-group 0..3
    const int hbase = blockIdx.x * NT;
    const int s     = blockIdx.y;
    const int kbase = s * KC;

    // ---- stage A: 32 x 1KB wave-chunks; chunk m covers rows 2m,2m+1.
    // lane l -> LDS position l (linear, HW-enforced); source chunk inverse-
    // swizzled so row r's chunk c lands at position c^(r&7).
    #pragma unroll
    for (int i = 0; i < 8; ++i) {
        const int m = w * 8 + i;
        const int r = 2 * m + (l >> 5);
        const int c = (l & 31) ^ (r & 7);       // 16B = 8 bf16 chunk
        load_lds16(g_bf + (size_t)r * KDIM + kbase + c * 8,
                   alds + m * 512);
    }
    // ---- stage W: 16 x 1KB wave-chunks; chunk = one fp32 row of 64x16B.
    #pragma unroll
    for (int i = 0; i < 4; ++i) {
        const int r = w * 4 + i;
        const int c = l ^ (r & 7);              // 16B = 4 float chunk
        load_lds16(W + (size_t)(hbase + r) * FAN + kbase + c * 4,
                   wlds + r * KC);
    }
    asm volatile("s_waitcnt vmcnt(0)" ::: "memory");
    __syncthreads();

    f32x4 acc = (f32x4){0.f, 0.f, 0.f, 0.f};
    const int ra = w * 16 + l15;                // A row (b)
    const int rb = l15;                         // W row (h offset)

    #pragma unroll
    for (int ks = 0; ks < 8; ++ks) {
        // A fragment: source chunk ca at swizzled position ca^(ra&7)
        const int ca = ks * 4 + lk;
        const bf16x8 afrag =
            *(const bf16x8*)(alds + ra * KC + ((ca ^ (ra & 7)) << 3));

        // B fragment: 8 floats = chunks cb, cb+1 (cb even), swizzled; cvt_pk
        const int cb = ks * 8 + lk * 2;
        const float4 f0 = *(const float4*)(wlds + rb * KC + (((cb    ) ^ (rb & 7)) << 2));
        const float4 f1 = *(const float4*)(wlds + rb * KC + (((cb + 1) ^ (rb & 7)) << 2));
        union { unsigned u[4]; bf16x8 v; } bb;
        bb.u[0] = cvt_pk(f0.x, f0.y);
        bb.u[1] = cvt_pk(f0.z, f0.w);
        bb.u[2] = cvt_pk(f1.x, f1.y);
        bb.u[3] = cvt_pk(f1.z, f1.w);

        acc = __builtin_amdgcn_mfma_f32_16x16x32_bf16(afrag, bb.v, acc, 0, 0, 0);
    }

    // C/D layout: col = lane&15 (h offset), row = (lane>>4)*4 + reg (b offset)
    const int h = hbase + l15;
    #pragma unroll
    for (int rr = 0; rr < 4; ++rr) {
        const int b = w * 16 + lk * 4 + rr;
        float v = acc[rr];
        if (s == 0)
            v += bias[h] + l_t[b] * W[(size_t)h * FAN + KDIM];
        atomicAdd(&out[(size_t)b * NHID + h], v);
    }
}

extern "C" void kernel_launch(void* const* d_in, const int* in_sizes, int n_in,
                              void* d_out, int out_size, void* d_ws, size_t ws_size,
                              hipStream_t stream) {
    const float* vals  = (const float*)d_in[0];
    const float* time_ = (const float*)d_in[1];
    const int*   masks = (const int*)d_in[2];
    // d_in[3] = lengths (all == T, unused)
    const float* l_t   = (const float*)d_in[4];
    const float* W     = (const float*)d_in[5];
    const float* bias  = (const float*)d_in[6];

    float* out  = (float*)d_out;                 // grep [B, NHID]
    float* out2 = out + (size_t)B * NHID;        // g[:, 2048]  [B]
    unsigned short* g_bf = (unsigned short*)d_ws; // bf16 [B][KDIM] = 512 KB

    dim3 g1(B, NQ);
    glimpse_kernel<<<g1, 64, 0, stream>>>(vals, time_, masks, l_t, g_bf, out2, out);

    dim3 g2(NHID / NT, SPLITS);
    gemm_mfma<<<g2, 256, 0, stream>>>(g_bf, l_t, W, bias, out);
}